// Round 1
// baseline (1045.863 us; speedup 1.0000x reference)
//
#include <hip/hip_runtime.h>
#include <hip/hip_bf16.h>
#include <math.h>

#define LYR   2
#define H     512
#define NH    32
#define BATCH 8
#define SEQL  4096
#define QC    64            // scan chunk length
#define NC    (SEQL / QC)   // 64 chunks
#define MROWS (BATCH * SEQL)

typedef __attribute__((ext_vector_type(8))) short short8;
typedef __attribute__((ext_vector_type(4))) float floatx4;

__device__ __forceinline__ float gelu_f(float x) {
    return 0.5f * x * (1.0f + erff(x * 0.70710678118654752440f));
}

// ---------------------------------------------------------------------------
// Weight cast + transpose: W[l][k][n] fp32 -> Wt[l][n][k] bf16
// ---------------------------------------------------------------------------
__global__ void cast_w_kernel(const float* __restrict__ W, __hip_bfloat16* __restrict__ Wt) {
    __shared__ float tile[64][65];
    const int l  = blockIdx.z;
    const int k0 = blockIdx.y * 64;
    const int n0 = blockIdx.x * 64;
    const float* src = W + (size_t)l * H * H;
    __hip_bfloat16* dst = Wt + (size_t)l * H * H;
#pragma unroll
    for (int i = 0; i < 16; i++) {
        int e = i * 256 + threadIdx.x;
        int r = e >> 6, c = e & 63;
        tile[r][c] = src[(size_t)(k0 + r) * H + n0 + c];
    }
    __syncthreads();
#pragma unroll
    for (int i = 0; i < 16; i++) {
        int e = i * 256 + threadIdx.x;
        int r = e >> 6, c = e & 63;  // r = local n, c = local k
        dst[(size_t)(n0 + r) * H + k0 + c] = __float2bfloat16(tile[c][r]);
    }
}

// ---------------------------------------------------------------------------
// SSM discretization: dA = exp(dt*A), coef = C * B * (dA-1)/A, dAQ = dA^QC
// ---------------------------------------------------------------------------
__global__ void ssm_params_kernel(const float* __restrict__ log_dt,
                                  const float* __restrict__ A_re, const float* __restrict__ A_im,
                                  const float* __restrict__ B_re, const float* __restrict__ B_im,
                                  const float* __restrict__ C_re, const float* __restrict__ C_im,
                                  float* __restrict__ dA, float* __restrict__ coef,
                                  float* __restrict__ dAQ) {
    const int idx = blockIdx.x * 256 + threadIdx.x;   // (l*H + h)*NH + n
    if (idx >= LYR * H * NH) return;
    const int lh = idx >> 5;
    const float dt  = expf(log_dt[lh]);
    const float are = A_re[idx], aim = A_im[idx];
    const float e   = expf(dt * are);
    const float dre = e * cosf(dt * aim);
    const float dim_ = e * sinf(dt * aim);
    // (dA - 1) / A
    const float den = are * are + aim * aim;
    const float nre = dre - 1.0f, nim = dim_;
    const float qre = (nre * are + nim * aim) / den;
    const float qim = (nim * are - nre * aim) / den;
    // dB = (Bre + i Bim) * q ; coef = (Cre + i Cim) * dB
    const float bre = B_re[idx], bim = B_im[idx];
    const float dbre = bre * qre - bim * qim;
    const float dbim = bre * qim + bim * qre;
    const float cre = C_re[idx], cim = C_im[idx];
    coef[2 * idx]     = cre * dbre - cim * dbim;
    coef[2 * idx + 1] = cre * dbim + cim * dbre;
    dA[2 * idx]     = dre;
    dA[2 * idx + 1] = dim_;
    const float eq = expf((float)QC * dt * are);
    const float ph = (float)QC * dt * aim;
    dAQ[2 * idx]     = eq * cosf(ph);
    dAQ[2 * idx + 1] = eq * sinf(ph);
}

// ---------------------------------------------------------------------------
// LayerNorm over H=512, one wave per row (4 rows / 256-thread block)
// ---------------------------------------------------------------------------
template <int OUT_BF16>
__global__ void ln_kernel(const float* __restrict__ src,
                          const float* __restrict__ gamma, const float* __restrict__ beta,
                          float* __restrict__ outf, __hip_bfloat16* __restrict__ outb) {
    const int lane = threadIdx.x & 63;
    const int row  = blockIdx.x * 4 + (threadIdx.x >> 6);
    const float4* rp = (const float4*)(src + (size_t)row * H);
    float4 v0 = rp[lane];
    float4 v1 = rp[64 + lane];
    float s = v0.x + v0.y + v0.z + v0.w + v1.x + v1.y + v1.z + v1.w;
    float q = v0.x * v0.x + v0.y * v0.y + v0.z * v0.z + v0.w * v0.w +
              v1.x * v1.x + v1.y * v1.y + v1.z * v1.z + v1.w * v1.w;
#pragma unroll
    for (int off = 32; off > 0; off >>= 1) {
        s += __shfl_xor(s, off);
        q += __shfl_xor(q, off);
    }
    const float mean = s * (1.0f / H);
    const float var  = q * (1.0f / H) - mean * mean;
    const float rstd = rsqrtf(var + 1e-5f);
    const float4* gp = (const float4*)gamma;
    const float4* bp = (const float4*)beta;
    float4 g0 = gp[lane], g1 = gp[64 + lane];
    float4 b0 = bp[lane], b1 = bp[64 + lane];
    float4 z0, z1;
    z0.x = (v0.x - mean) * rstd * g0.x + b0.x;
    z0.y = (v0.y - mean) * rstd * g0.y + b0.y;
    z0.z = (v0.z - mean) * rstd * g0.z + b0.z;
    z0.w = (v0.w - mean) * rstd * g0.w + b0.w;
    z1.x = (v1.x - mean) * rstd * g1.x + b1.x;
    z1.y = (v1.y - mean) * rstd * g1.y + b1.y;
    z1.z = (v1.z - mean) * rstd * g1.z + b1.z;
    z1.w = (v1.w - mean) * rstd * g1.w + b1.w;
    if (OUT_BF16) {
        __hip_bfloat16 t0[4] = {__float2bfloat16(z0.x), __float2bfloat16(z0.y),
                                __float2bfloat16(z0.z), __float2bfloat16(z0.w)};
        __hip_bfloat16 t1[4] = {__float2bfloat16(z1.x), __float2bfloat16(z1.y),
                                __float2bfloat16(z1.z), __float2bfloat16(z1.w)};
        *(uint2*)(outb + (size_t)row * H + lane * 4)       = *(uint2*)t0;
        *(uint2*)(outb + (size_t)row * H + 256 + lane * 4) = *(uint2*)t1;
    } else {
        float4* op = (float4*)(outf + (size_t)row * H);
        op[lane]      = z0;
        op[64 + lane] = z1;
    }
}

// ---------------------------------------------------------------------------
// Conv pass 1: per-chunk local final states (zero initial state)
// block: 256 threads = 128 h-channels x 2 (16 modes each)
// grid: BATCH * NC * 4
// ---------------------------------------------------------------------------
__global__ void conv_pass1(const float* __restrict__ z, const float* __restrict__ dA,
                           float* __restrict__ S) {
    const int blk = blockIdx.x;
    const int b   = blk / (NC * 4);
    const int rem = blk % (NC * 4);
    const int c   = rem >> 2;
    const int h   = (rem & 3) * 128 + (threadIdx.x >> 1);
    const int nb  = (threadIdx.x & 1) * 16;

    float dre[16], dim_[16], sre[16], sim[16];
    const float4* dp = (const float4*)(dA + ((size_t)h * NH + nb) * 2);
#pragma unroll
    for (int j = 0; j < 8; j++) {
        float4 v = dp[j];
        dre[2 * j] = v.x; dim_[2 * j] = v.y; dre[2 * j + 1] = v.z; dim_[2 * j + 1] = v.w;
        sre[2 * j] = 0.f; sim[2 * j] = 0.f; sre[2 * j + 1] = 0.f; sim[2 * j + 1] = 0.f;
    }
    const float* up = z + ((size_t)b * SEQL + (size_t)c * QC) * H + h;
    for (int t = 0; t < QC; t++) {
        const float u = up[(size_t)t * H];
#pragma unroll
        for (int m = 0; m < 16; m++) {
            const float nr = fmaf(dre[m], sre[m], fmaf(-dim_[m], sim[m], u));
            const float ni = fmaf(dre[m], sim[m], dim_[m] * sre[m]);
            sre[m] = nr; sim[m] = ni;
        }
    }
    float4* Sp = (float4*)(S + (((size_t)(b * NC + c) * H + h) * NH + nb) * 2);
#pragma unroll
    for (int j = 0; j < 8; j++) {
        float4 v;
        v.x = sre[2 * j]; v.y = sim[2 * j]; v.z = sre[2 * j + 1]; v.w = sim[2 * j + 1];
        Sp[j] = v;
    }
}

// ---------------------------------------------------------------------------
// Conv pass 2: sequential scan over chunks; converts local states -> initial
// states in place. One thread per (b,h,n).
// ---------------------------------------------------------------------------
__global__ void conv_scan(float* __restrict__ S, const float* __restrict__ dAQ) {
    const int idx = blockIdx.x * blockDim.x + threadIdx.x;  // b*(H*NH) + h*NH + n
    const int b   = idx / (H * NH);
    const int hn  = idx - b * (H * NH);
    const float2 qv = ((const float2*)dAQ)[hn];
    float rre = 0.f, rim = 0.f;
    for (int c = 0; c < NC; c++) {
        float2* p = (float2*)(S + (((size_t)(b * NC + c) * H) * NH + hn) * 2);
        const float2 lv = *p;
        float2 w; w.x = rre; w.y = rim;
        *p = w;
        const float tre = qv.x * rre - qv.y * rim + lv.x;
        const float tim = qv.x * rim + qv.y * rre + lv.y;
        rre = tre; rim = tim;
    }
}

// ---------------------------------------------------------------------------
// Conv pass 3: recompute states from initial state, emit
// y = gelu( 2*Re(sum_n coef*s) + z*D ) as bf16
// ---------------------------------------------------------------------------
__global__ void conv_pass3(const float* __restrict__ z, const float* __restrict__ dA,
                           const float* __restrict__ coef, const float* __restrict__ S,
                           const float* __restrict__ Dv, __hip_bfloat16* __restrict__ yb) {
    const int blk = blockIdx.x;
    const int b   = blk / (NC * 4);
    const int rem = blk % (NC * 4);
    const int c   = rem >> 2;
    const int h   = (rem & 3) * 128 + (threadIdx.x >> 1);
    const int nb  = (threadIdx.x & 1) * 16;

    float dre[16], dim_[16], cre[16], cim_[16], sre[16], sim[16];
    const float4* dp = (const float4*)(dA + ((size_t)h * NH + nb) * 2);
    const float4* cp = (const float4*)(coef + ((size_t)h * NH + nb) * 2);
    const float4* Sp = (const float4*)(S + (((size_t)(b * NC + c) * H + h) * NH + nb) * 2);
#pragma unroll
    for (int j = 0; j < 8; j++) {
        float4 v = dp[j];
        dre[2 * j] = v.x; dim_[2 * j] = v.y; dre[2 * j + 1] = v.z; dim_[2 * j + 1] = v.w;
        float4 w = cp[j];
        cre[2 * j] = w.x; cim_[2 * j] = w.y; cre[2 * j + 1] = w.z; cim_[2 * j + 1] = w.w;
        float4 s0 = Sp[j];
        sre[2 * j] = s0.x; sim[2 * j] = s0.y; sre[2 * j + 1] = s0.z; sim[2 * j + 1] = s0.w;
    }
    const float Dh = Dv[h];
    const float* up = z + ((size_t)b * SEQL + (size_t)c * QC) * H + h;
    __hip_bfloat16* yp = yb + ((size_t)b * SEQL + (size_t)c * QC) * H + h;
    for (int t = 0; t < QC; t++) {
        const float u = up[(size_t)t * H];
        float acc = 0.f;
#pragma unroll
        for (int m = 0; m < 16; m++) {
            const float nr = fmaf(dre[m], sre[m], fmaf(-dim_[m], sim[m], u));
            const float ni = fmaf(dre[m], sim[m], dim_[m] * sre[m]);
            sre[m] = nr; sim[m] = ni;
            acc = fmaf(cre[m], nr, acc);
            acc = fmaf(-cim_[m], ni, acc);
        }
        const float other = __shfl_xor(acc, 1);
        if ((threadIdx.x & 1) == 0) {
            const float yv = 2.0f * (acc + other) + u * Dh;
            yp[(size_t)t * H] = __float2bfloat16(gelu_f(yv));
        }
    }
}

// ---------------------------------------------------------------------------
// bf16 MFMA GEMM: C[M,512] = A[M,K] @ W[K,512] (+bias, +res, gelu, dual)
// A: bf16 row-major [M][512]; Wt: bf16 [N][K] (pre-transposed)
// 128x128 block tile, BK=64, 256 threads (4 waves, 2x2 of 64x64)
// ---------------------------------------------------------------------------
#define BM 128
#define BN 128
#define BK 64
#define LDK (BK + 8)

enum { M_BIAS = 0, M_RES = 1, M_GELU = 2, M_DUAL = 3 };

template <int MODE>
__global__ void gemm_kernel(const __hip_bfloat16* __restrict__ A1,
                            const __hip_bfloat16* __restrict__ Wt1,
                            const __hip_bfloat16* __restrict__ A2,
                            const __hip_bfloat16* __restrict__ Wt2,
                            const float* __restrict__ bias1, const float* __restrict__ bias2,
                            const float* __restrict__ res,
                            float* __restrict__ outf, __hip_bfloat16* __restrict__ outb,
                            int KTOT) {
    __shared__ __hip_bfloat16 As[BM][LDK];
    __shared__ __hip_bfloat16 Bs[BN][LDK];
    const int tid  = threadIdx.x;
    const int lane = tid & 63;
    const int wid  = tid >> 6;
    const int wm   = (wid >> 1) * 64;
    const int wn   = (wid & 1) * 64;
    const int m0   = blockIdx.y * BM;
    const int n0   = blockIdx.x * BN;

    floatx4 acc[4][4] = {};

    for (int k0 = 0; k0 < KTOT; k0 += BK) {
        const __hip_bfloat16* Ap;
        const __hip_bfloat16* Wp;
        int kk = k0;
        if (MODE == M_DUAL && k0 >= 512) {
            Ap = A2; Wp = Wt2; kk = k0 - 512;
        } else {
            Ap = A1; Wp = Wt1;
        }
#pragma unroll
        for (int i = 0; i < 4; i++) {
            const int idx = i * 256 + tid;
            const int r   = idx >> 3;
            const int c8  = (idx & 7) << 3;
            *(floatx4*)&As[r][c8] = *(const floatx4*)(Ap + (size_t)(m0 + r) * 512 + kk + c8);
            *(floatx4*)&Bs[r][c8] = *(const floatx4*)(Wp + (size_t)(n0 + r) * 512 + kk + c8);
        }
        __syncthreads();
#pragma unroll
        for (int ks = 0; ks < BK; ks += 32) {
            short8 af[4], bfr[4];
#pragma unroll
            for (int mt = 0; mt < 4; mt++)
                af[mt] = *(const short8*)&As[wm + mt * 16 + (lane & 15)][ks + (lane >> 4) * 8];
#pragma unroll
            for (int nt = 0; nt < 4; nt++)
                bfr[nt] = *(const short8*)&Bs[wn + nt * 16 + (lane & 15)][ks + (lane >> 4) * 8];
#pragma unroll
            for (int mt = 0; mt < 4; mt++)
#pragma unroll
                for (int nt = 0; nt < 4; nt++)
                    acc[mt][nt] = __builtin_amdgcn_mfma_f32_16x16x32_bf16(
                        af[mt], bfr[nt], acc[mt][nt], 0, 0, 0);
        }
        __syncthreads();
    }

#pragma unroll
    for (int mt = 0; mt < 4; mt++) {
        const int rbase = m0 + wm + mt * 16 + ((lane >> 4) << 2);
#pragma unroll
        for (int nt = 0; nt < 4; nt++) {
            const int col = n0 + wn + nt * 16 + (lane & 15);
            float bsum = bias1[col];
            if constexpr (MODE == M_DUAL) bsum += bias2[col];
#pragma unroll
            for (int r = 0; r < 4; r++) {
                const int row = rbase + r;
                float v = acc[mt][nt][r] + bsum;
                if constexpr (MODE == M_RES) v += res[(size_t)row * H + col];
                if constexpr (MODE == M_GELU) v = gelu_f(v);
                const size_t o = (size_t)row * H + col;
                if constexpr (MODE == M_RES || MODE == M_DUAL) outf[o] = v;
                if constexpr (MODE != M_DUAL) outb[o] = __float2bfloat16(v);
            }
        }
    }
}

// ---------------------------------------------------------------------------
extern "C" void kernel_launch(void* const* d_in, const int* in_sizes, int n_in,
                              void* d_out, int out_size, void* d_ws, size_t ws_size,
                              hipStream_t stream) {
    const float* x     = (const float*)d_in[0];
    const float* ln1w  = (const float*)d_in[1];
    const float* ln1b  = (const float*)d_in[2];
    const float* ln2w  = (const float*)d_in[3];
    const float* ln2b  = (const float*)d_in[4];
    const float* logdt = (const float*)d_in[5];
    const float* Are   = (const float*)d_in[6];
    const float* Aim   = (const float*)d_in[7];
    const float* Bre   = (const float*)d_in[8];
    const float* Bim   = (const float*)d_in[9];
    const float* Cre   = (const float*)d_in[10];
    const float* Cim   = (const float*)d_in[11];
    const float* Dvec  = (const float*)d_in[12];
    const float* Wk    = (const float*)d_in[13];
    const float* bk    = (const float*)d_in[14];
    const float* W1    = (const float*)d_in[15];
    const float* b1    = (const float*)d_in[16];
    const float* W2    = (const float*)d_in[17];
    const float* b2    = (const float*)d_in[18];
    const float* Wout  = (const float*)d_in[19];
    const float* bout  = (const float*)d_in[20];
    const float* Wproj = (const float*)d_in[21];
    const float* bproj = (const float*)d_in[22];
    float* outp = (float*)d_out;

    char* p = (char*)d_ws;
    auto carve = [&](size_t bytes) -> char* {
        char* r = p;
        p += (bytes + 255) & ~(size_t)255;
        return r;
    };
    float* zbuf = (float*)carve((size_t)MROWS * H * 4);                 // 64 MB (z, then o1)
    float* Sbuf = (float*)carve((size_t)BATCH * NC * H * NH * 2 * 4);   // 64 MB
    __hip_bfloat16* bb0 = (__hip_bfloat16*)carve((size_t)MROWS * H * 2);  // 32 MB
    __hip_bfloat16* bb1 = (__hip_bfloat16*)carve((size_t)MROWS * H * 2);
    __hip_bfloat16* bb2 = (__hip_bfloat16*)carve((size_t)MROWS * H * 2);
    float* dAb  = (float*)carve((size_t)LYR * H * NH * 2 * 4);
    float* cfb  = (float*)carve((size_t)LYR * H * NH * 2 * 4);
    float* dAQb = (float*)carve((size_t)LYR * H * NH * 2 * 4);
    __hip_bfloat16* wts[5];
    for (int i = 0; i < 5; i++) wts[i] = (__hip_bfloat16*)carve((size_t)LYR * H * H * 2);

    const float* wsrc[5] = {Wk, W1, W2, Wout, Wproj};
    {
        dim3 g(8, 8, LYR);
        for (int i = 0; i < 5; i++)
            cast_w_kernel<<<g, 256, 0, stream>>>(wsrc[i], wts[i]);
    }
    ssm_params_kernel<<<(LYR * H * NH) / 256, 256, 0, stream>>>(
        logdt, Are, Aim, Bre, Bim, Cre, Cim, dAb, cfb, dAQb);

    const float* cur = x;
    for (int l = 0; l < LYR; l++) {
        const float* dAl  = dAb + (size_t)l * H * NH * 2;
        const float* cfl  = cfb + (size_t)l * H * NH * 2;
        const float* dAQl = dAQb + (size_t)l * H * NH * 2;

        ln_kernel<0><<<MROWS / 4, 256, 0, stream>>>(cur, ln1w + l * H, ln1b + l * H, zbuf, nullptr);
        conv_pass1<<<BATCH * NC * 4, 256, 0, stream>>>(zbuf, dAl, Sbuf);
        conv_scan<<<(BATCH * H * NH) / 256, 256, 0, stream>>>(Sbuf, dAQl);
        conv_pass3<<<BATCH * NC * 4, 256, 0, stream>>>(zbuf, dAl, cfl, Sbuf, Dvec + l * H, bb0);

        dim3 gg(H / BN, MROWS / BM);
        // y1 = y @ Wk + bk                      -> bb1 (bf16)
        gemm_kernel<M_BIAS><<<gg, 256, 0, stream>>>(
            bb0, wts[0] + (size_t)l * H * H, nullptr, nullptr,
            bk + l * H, nullptr, nullptr, nullptr, bb1, 512);
        // o1 = y1 @ W1 + b1 + cur               -> zbuf (fp32) + bb0 (bf16)
        gemm_kernel<M_RES><<<gg, 256, 0, stream>>>(
            bb1, wts[1] + (size_t)l * H * H, nullptr, nullptr,
            b1 + l * H, nullptr, cur, zbuf, bb0, 512);
        // z2 = LN(o1)                           -> bb1 (bf16)
        ln_kernel<1><<<MROWS / 4, 256, 0, stream>>>(zbuf, ln2w + l * H, ln2b + l * H, nullptr, bb1);
        // h = gelu(z2 @ W2 + b2)                -> bb2 (bf16)
        gemm_kernel<M_GELU><<<gg, 256, 0, stream>>>(
            bb1, wts[2] + (size_t)l * H * H, nullptr, nullptr,
            b2 + l * H, nullptr, nullptr, nullptr, bb2, 512);
        // out = h @ Wout + bout + o1 @ Wproj + bproj  -> d_out (fp32)
        gemm_kernel<M_DUAL><<<gg, 256, 0, stream>>>(
            bb2, wts[3] + (size_t)l * H * H, bb0, wts[4] + (size_t)l * H * H,
            bout + l * H, bproj + l * H, nullptr, outp, nullptr, 1024);
        cur = outp;
    }
}

// Round 4
// 953.587 us; speedup vs baseline: 1.0968x; 1.0968x over previous
//
#include <hip/hip_runtime.h>
#include <hip/hip_bf16.h>
#include <math.h>

#define LYR   2
#define H     512
#define NH    32
#define BATCH 8
#define SEQL  4096
#define QC    64
#define NC    (SEQL / QC)
#define MROWS (BATCH * SEQL)

typedef __attribute__((ext_vector_type(8))) short short8;
typedef __attribute__((ext_vector_type(4))) float floatx4;
typedef __hip_bfloat16 bf16;

__device__ __forceinline__ float gelu_f(float x) {
    return 0.5f * x * (1.0f + erff(x * 0.70710678118654752440f));
}

__device__ __forceinline__ void glds16(const void* g, void* l) {
    __builtin_amdgcn_global_load_lds((const __attribute__((address_space(1))) void*)g,
                                     (__attribute__((address_space(3))) void*)l, 16, 0, 0);
}

// ---------------------------------------------------------------------------
// Weight cast + transpose: W[l][k][n] fp32 -> Wt[l][n][k] bf16
// ---------------------------------------------------------------------------
__global__ void cast_w_kernel(const float* __restrict__ W, bf16* __restrict__ Wt) {
    __shared__ __align__(16) float tile[64][65];
    const int l  = blockIdx.z;
    const int k0 = blockIdx.y * 64;
    const int n0 = blockIdx.x * 64;
    const float* src = W + (size_t)l * H * H;
    bf16* dst = Wt + (size_t)l * H * H;
#pragma unroll
    for (int i = 0; i < 16; i++) {
        int e = i * 256 + threadIdx.x;
        int r = e >> 6, c = e & 63;
        tile[r][c] = src[(size_t)(k0 + r) * H + n0 + c];
    }
    __syncthreads();
#pragma unroll
    for (int i = 0; i < 16; i++) {
        int e = i * 256 + threadIdx.x;
        int r = e >> 6, c = e & 63;
        dst[(size_t)(n0 + r) * H + k0 + c] = __float2bfloat16(tile[c][r]);
    }
}

// ---------------------------------------------------------------------------
// SSM discretization: dA = exp(dt*A), coef = C*B*(dA-1)/A, dAQ = dA^QC
// ---------------------------------------------------------------------------
__global__ void ssm_params_kernel(const float* __restrict__ log_dt,
                                  const float* __restrict__ A_re, const float* __restrict__ A_im,
                                  const float* __restrict__ B_re, const float* __restrict__ B_im,
                                  const float* __restrict__ C_re, const float* __restrict__ C_im,
                                  float* __restrict__ dA, float* __restrict__ coef,
                                  float* __restrict__ dAQ) {
    const int idx = blockIdx.x * 256 + threadIdx.x;
    if (idx >= LYR * H * NH) return;
    const int lh = idx >> 5;
    const float dt  = expf(log_dt[lh]);
    const float are = A_re[idx], aim = A_im[idx];
    const float e   = expf(dt * are);
    const float dre = e * cosf(dt * aim);
    const float dim_ = e * sinf(dt * aim);
    const float den = are * are + aim * aim;
    const float nre = dre - 1.0f, nim = dim_;
    const float qre = (nre * are + nim * aim) / den;
    const float qim = (nim * are - nre * aim) / den;
    const float bre = B_re[idx], bim = B_im[idx];
    const float dbre = bre * qre - bim * qim;
    const float dbim = bre * qim + bim * qre;
    const float cre = C_re[idx], cim = C_im[idx];
    coef[2 * idx]     = cre * dbre - cim * dbim;
    coef[2 * idx + 1] = cre * dbim + cim * dbre;
    dA[2 * idx]     = dre;
    dA[2 * idx + 1] = dim_;
    const float eq = expf((float)QC * dt * are);
    const float ph = (float)QC * dt * aim;
    dAQ[2 * idx]     = eq * cosf(ph);
    dAQ[2 * idx + 1] = eq * sinf(ph);
}

// ---------------------------------------------------------------------------
// Build per-(l,h) conv matrices:
//   M1b[lh][j][tau]  (64x64): j=2n -> Re(dA^{63-tau}), j=2n+1 -> Im
//   TEb[lh][t][192]: [0:64] T[t][tau]=K[t-tau] (t>=tau) + D_h diag
//                    [64:128] E (for S0 hi), [128:192] E (for S0 lo)
// ---------------------------------------------------------------------------
__global__ void prep_mats(const float* __restrict__ dA, const float* __restrict__ coef,
                          const float* __restrict__ Dv,
                          bf16* __restrict__ M1b, bf16* __restrict__ TEb) {
    const int lh = blockIdx.x;
    const int t  = threadIdx.x;
    __shared__ float Ksh[64];
    const float* dAp = dA + (size_t)lh * NH * 2;
    const float* cfp = coef + (size_t)lh * NH * 2;
    bf16* terow = TEb + ((size_t)lh * 64 + t) * 192;
    float Kt = 0.f;
    for (int n = 0; n < NH; n++) {
        const float dre = dAp[2 * n], dim_ = dAp[2 * n + 1];
        const float cre = cfp[2 * n], cim = cfp[2 * n + 1];
        float pr = 1.f, pi = 0.f;                       // dA^t
        for (int i = 0; i < t; i++) { float tr = pr * dre - pi * dim_; pi = pr * dim_ + pi * dre; pr = tr; }
        Kt += 2.f * (cre * pr - cim * pi);
        const float per = pr * dre - pi * dim_;         // dA^{t+1}
        const float pei = pr * dim_ + pi * dre;
        const float e0 = 2.f * (cre * per - cim * pei);
        const float e1 = -2.f * (cre * pei + cim * per);
        terow[64 + 2 * n]      = __float2bfloat16(e0);
        terow[64 + 2 * n + 1]  = __float2bfloat16(e1);
        terow[128 + 2 * n]     = __float2bfloat16(e0);
        terow[128 + 2 * n + 1] = __float2bfloat16(e1);
        float qr = 1.f, qi = 0.f;                       // dA^{63-t}
        for (int i = 0; i < 63 - t; i++) { float tr = qr * dre - qi * dim_; qi = qr * dim_ + qi * dre; qr = tr; }
        M1b[((size_t)lh * 64 + 2 * n) * 64 + t]     = __float2bfloat16(qr);
        M1b[((size_t)lh * 64 + 2 * n + 1) * 64 + t] = __float2bfloat16(qi);
    }
    Ksh[t] = Kt;
    __syncthreads();
    const float Dh = Dv[lh];
    for (int tau = 0; tau < 64; tau++) {
        float v = (tau > t) ? 0.f : Ksh[t - tau];
        if (tau == t) v += Dh;
        terow[tau] = __float2bfloat16(v);
    }
}

// ---------------------------------------------------------------------------
// LayerNorm over H=512, one wave per row, bf16 out
// ---------------------------------------------------------------------------
__global__ void ln_kernel(const float* __restrict__ src,
                          const float* __restrict__ gamma, const float* __restrict__ beta,
                          bf16* __restrict__ outb) {
    const int lane = threadIdx.x & 63;
    const int row  = blockIdx.x * 4 + (threadIdx.x >> 6);
    const float4* rp = (const float4*)(src + (size_t)row * H);
    float4 v0 = rp[lane];
    float4 v1 = rp[64 + lane];
    float s = v0.x + v0.y + v0.z + v0.w + v1.x + v1.y + v1.z + v1.w;
    float q = v0.x * v0.x + v0.y * v0.y + v0.z * v0.z + v0.w * v0.w +
              v1.x * v1.x + v1.y * v1.y + v1.z * v1.z + v1.w * v1.w;
#pragma unroll
    for (int off = 32; off > 0; off >>= 1) {
        s += __shfl_xor(s, off);
        q += __shfl_xor(q, off);
    }
    const float mean = s * (1.0f / H);
    const float var  = q * (1.0f / H) - mean * mean;
    const float rstd = rsqrtf(var + 1e-5f);
    const float4* gp = (const float4*)gamma;
    const float4* bp = (const float4*)beta;
    float4 g0 = gp[lane], g1 = gp[64 + lane];
    float4 b0 = bp[lane], b1 = bp[64 + lane];
    bf16 t0[4] = {__float2bfloat16((v0.x - mean) * rstd * g0.x + b0.x),
                  __float2bfloat16((v0.y - mean) * rstd * g0.y + b0.y),
                  __float2bfloat16((v0.z - mean) * rstd * g0.z + b0.z),
                  __float2bfloat16((v0.w - mean) * rstd * g0.w + b0.w)};
    bf16 t1[4] = {__float2bfloat16((v1.x - mean) * rstd * g1.x + b1.x),
                  __float2bfloat16((v1.y - mean) * rstd * g1.y + b1.y),
                  __float2bfloat16((v1.z - mean) * rstd * g1.z + b1.z),
                  __float2bfloat16((v1.w - mean) * rstd * g1.w + b1.w)};
    *(uint2*)(outb + (size_t)row * H + lane * 4)       = *(uint2*)t0;
    *(uint2*)(outb + (size_t)row * H + 256 + lane * 4) = *(uint2*)t1;
}

// ---------------------------------------------------------------------------
// Transpose z[b,t,h] bf16 -> Ub[h][bc][tau] bf16   (bc = b*64+c, t = c*64+tau)
// ---------------------------------------------------------------------------
__global__ void trans_in_k(const bf16* __restrict__ z, bf16* __restrict__ Ub) {
    const int hb = blockIdx.x & 7, bc = blockIdx.x >> 3;
    const int b = bc >> 6, c = bc & 63;
    const int h0 = hb * 64;
    __shared__ __align__(16) ushort Ti[64][68];
    const ushort* zp = (const ushort*)z + ((size_t)b * SEQL + c * QC) * H + h0;
#pragma unroll
    for (int i = 0; i < 4; i++) {
        int tau = i * 16 + (threadIdx.x >> 4), h4 = (threadIdx.x & 15) * 4;
        *(ushort4*)&Ti[tau][h4] = *(const ushort4*)(zp + (size_t)tau * H + h4);
    }
    __syncthreads();
    ushort* up = (ushort*)Ub + ((size_t)h0 * 512 + bc) * 64;
#pragma unroll
    for (int i = 0; i < 4; i++) {
        int hh = i * 16 + (threadIdx.x >> 4), t4 = (threadIdx.x & 15) * 4;
        ushort4 v;
        v.x = Ti[t4][hh]; v.y = Ti[t4 + 1][hh]; v.z = Ti[t4 + 2][hh]; v.w = Ti[t4 + 3][hh];
        *(ushort4*)(up + (size_t)hh * 512 * 64 + t4) = v;
    }
}

// ---------------------------------------------------------------------------
// Conv phase 1: Sloc[h][j][bc] (fp32) = M1[h](64x64) @ U[h](64 x 512-block)
// ---------------------------------------------------------------------------
__global__ void conv_p1(const bf16* __restrict__ M1l, const bf16* __restrict__ Ub,
                        float* __restrict__ Sloc) {
    const int h = blockIdx.x >> 2;
    const int n0 = (blockIdx.x & 3) * 128;
    __shared__ __align__(16) bf16 As[64][72];
    __shared__ __align__(16) bf16 Bs[128][72];
    const int tid = threadIdx.x, lane = tid & 63, wid = tid >> 6;
    const int wm = (wid & 1) * 32, wn = (wid >> 1) * 64;
#pragma unroll
    for (int i = 0; i < 2; i++) {
        int idx = i * 256 + tid, r = idx >> 3, c8 = (idx & 7) * 8;
        *(floatx4*)&As[r][c8] = *(const floatx4*)(M1l + ((size_t)h * 64 + r) * 64 + c8);
    }
#pragma unroll
    for (int i = 0; i < 4; i++) {
        int idx = i * 256 + tid, r = idx >> 3, c8 = (idx & 7) * 8;
        *(floatx4*)&Bs[r][c8] = *(const floatx4*)(Ub + ((size_t)h * 512 + n0 + r) * 64 + c8);
    }
    __syncthreads();
    floatx4 acc[2][4] = {};
#pragma unroll
    for (int ks = 0; ks < 64; ks += 32) {
        short8 af[2], bfr[4];
#pragma unroll
        for (int mt = 0; mt < 2; mt++)
            af[mt] = *(const short8*)&As[wm + mt * 16 + (lane & 15)][ks + (lane >> 4) * 8];
#pragma unroll
        for (int nt = 0; nt < 4; nt++)
            bfr[nt] = *(const short8*)&Bs[wn + nt * 16 + (lane & 15)][ks + (lane >> 4) * 8];
#pragma unroll
        for (int mt = 0; mt < 2; mt++)
#pragma unroll
            for (int nt = 0; nt < 4; nt++)
                acc[mt][nt] = __builtin_amdgcn_mfma_f32_16x16x32_bf16(af[mt], bfr[nt], acc[mt][nt], 0, 0, 0);
    }
#pragma unroll
    for (int mt = 0; mt < 2; mt++)
#pragma unroll
        for (int nt = 0; nt < 4; nt++) {
            const int bc = n0 + wn + nt * 16 + (lane & 15);
#pragma unroll
            for (int r = 0; r < 4; r++) {
                const int j = wm + mt * 16 + ((lane >> 4) << 2) + r;
                Sloc[((size_t)h * 64 + j) * 512 + bc] = acc[mt][nt][r];
            }
        }
}

// ---------------------------------------------------------------------------
// Chunk scan: local end-states -> incoming states, hi/lo bf16 split
// ---------------------------------------------------------------------------
__global__ void conv_scan2(const float* __restrict__ Sloc, const float* __restrict__ dAQl,
                           bf16* __restrict__ S0b) {
    const int h = blockIdx.x >> 3, b = blockIdx.x & 7;
    const int tid = threadIdx.x;
    __shared__ __align__(16) float Sl[64][65];
    __shared__ __align__(16) bf16 Ob[64][128];
#pragma unroll
    for (int i = 0; i < 16; i++) {
        int j = i * 4 + (tid >> 6), c = tid & 63;
        Sl[j][c] = Sloc[((size_t)h * 64 + j) * 512 + b * 64 + c];
    }
    __syncthreads();
    if (tid < 32) {
        const int n = tid;
        const float qr = dAQl[(h * NH + n) * 2], qi = dAQl[(h * NH + n) * 2 + 1];
        float rr = 0.f, ri = 0.f;
        for (int c = 0; c < 64; c++) {
            bf16 hr = __float2bfloat16(rr);
            bf16 hi = __float2bfloat16(ri);
            Ob[c][2 * n]          = hr;
            Ob[c][2 * n + 1]      = hi;
            Ob[c][64 + 2 * n]     = __float2bfloat16(rr - __bfloat162float(hr));
            Ob[c][64 + 2 * n + 1] = __float2bfloat16(ri - __bfloat162float(hi));
            const float lr = Sl[2 * n][c], li = Sl[2 * n + 1][c];
            const float tr = qr * rr - qi * ri + lr;
            ri = qr * ri + qi * rr + li;
            rr = tr;
        }
    }
    __syncthreads();
    bf16* op = S0b + ((size_t)h * 512 + b * 64) * 128;
#pragma unroll
    for (int i = 0; i < 4; i++) {
        int idx = i * 256 + tid, c = idx >> 4, c8 = (idx & 15) * 8;
        *(floatx4*)(op + (size_t)c * 128 + c8) = *(const floatx4*)&Ob[c][c8];
    }
}

// ---------------------------------------------------------------------------
// Conv phase 3: Y[h] = [T|E|E](64x192) @ [U; S0hi; S0lo], gelu, -> Yt[h][bc][t]
// ---------------------------------------------------------------------------
__global__ void conv_p3(const bf16* __restrict__ TEl, const bf16* __restrict__ Ub,
                        const bf16* __restrict__ S0b, bf16* __restrict__ Yt) {
    const int h = blockIdx.x >> 2;
    const int n0 = (blockIdx.x & 3) * 128;
    __shared__ __align__(16) char sm3[(64 + 128) * 200 * 2];
    bf16(*As)[200] = (bf16(*)[200])sm3;
    bf16(*Bs)[200] = (bf16(*)[200])(sm3 + 64 * 200 * 2);
    const int tid = threadIdx.x, lane = tid & 63, wid = tid >> 6;
    const int wm = (wid & 1) * 32, wn = (wid >> 1) * 64;
#pragma unroll
    for (int i = 0; i < 6; i++) {
        int idx = i * 256 + tid, r = idx / 24, c = (idx - r * 24) * 8;
        *(floatx4*)&As[r][c] = *(const floatx4*)(TEl + ((size_t)h * 64 + r) * 192 + c);
    }
#pragma unroll
    for (int i = 0; i < 4; i++) {
        int idx = i * 256 + tid, r = idx >> 3, c8 = (idx & 7) * 8;
        *(floatx4*)&Bs[r][c8] = *(const floatx4*)(Ub + ((size_t)h * 512 + n0 + r) * 64 + c8);
    }
#pragma unroll
    for (int i = 0; i < 8; i++) {
        int idx = i * 256 + tid, r = idx >> 4, c8 = (idx & 15) * 8;
        *(floatx4*)&Bs[r][64 + c8] = *(const floatx4*)(S0b + ((size_t)h * 512 + n0 + r) * 128 + c8);
    }
    __syncthreads();
    floatx4 acc[2][4] = {};
#pragma unroll
    for (int ks = 0; ks < 192; ks += 32) {
        short8 af[2], bfr[4];
#pragma unroll
        for (int mt = 0; mt < 2; mt++)
            af[mt] = *(const short8*)&As[wm + mt * 16 + (lane & 15)][ks + (lane >> 4) * 8];
#pragma unroll
        for (int nt = 0; nt < 4; nt++)
            bfr[nt] = *(const short8*)&Bs[wn + nt * 16 + (lane & 15)][ks + (lane >> 4) * 8];
#pragma unroll
        for (int mt = 0; mt < 2; mt++)
#pragma unroll
            for (int nt = 0; nt < 4; nt++)
                acc[mt][nt] = __builtin_amdgcn_mfma_f32_16x16x32_bf16(af[mt], bfr[nt], acc[mt][nt], 0, 0, 0);
    }
    __syncthreads();
    bf16(*Tt)[72] = (bf16(*)[72])sm3;
#pragma unroll
    for (int mt = 0; mt < 2; mt++)
#pragma unroll
        for (int nt = 0; nt < 4; nt++) {
            const int n = wn + nt * 16 + (lane & 15);
#pragma unroll
            for (int r = 0; r < 4; r++) {
                const int t = wm + mt * 16 + ((lane >> 4) << 2) + r;
                Tt[n][t] = __float2bfloat16(gelu_f(acc[mt][nt][r]));
            }
        }
    __syncthreads();
#pragma unroll
    for (int i = 0; i < 4; i++) {
        int idx = i * 256 + tid, r = idx >> 3, c8 = (idx & 7) * 8;
        *(floatx4*)(Yt + ((size_t)h * 512 + n0 + r) * 64 + c8) = *(const floatx4*)&Tt[r][c8];
    }
}

// ---------------------------------------------------------------------------
// Transpose Yt[h][bc][t] -> y[b, c*64+t, h] bf16
// ---------------------------------------------------------------------------
__global__ void trans_out_k(const bf16* __restrict__ Yt, bf16* __restrict__ y) {
    const int hb = blockIdx.x & 7, bc = blockIdx.x >> 3;
    const int b = bc >> 6, c = bc & 63;
    const int h0 = hb * 64;
    __shared__ __align__(16) ushort Ti[64][68];
    const ushort* yp = (const ushort*)Yt + ((size_t)h0 * 512 + bc) * 64;
#pragma unroll
    for (int i = 0; i < 4; i++) {
        int hh = i * 16 + (threadIdx.x >> 4), t4 = (threadIdx.x & 15) * 4;
        *(ushort4*)&Ti[hh][t4] = *(const ushort4*)(yp + (size_t)hh * 512 * 64 + t4);
    }
    __syncthreads();
    ushort* op = (ushort*)y + ((size_t)b * SEQL + c * QC) * H + h0;
#pragma unroll
    for (int i = 0; i < 4; i++) {
        int tau = i * 16 + (threadIdx.x >> 4), h4 = (threadIdx.x & 15) * 4;
        ushort4 v;
        v.x = Ti[h4][tau]; v.y = Ti[h4 + 1][tau]; v.z = Ti[h4 + 2][tau]; v.w = Ti[h4 + 3][tau];
        *(ushort4*)(op + (size_t)tau * H + h4) = v;
    }
}

// ---------------------------------------------------------------------------
// bf16 MFMA GEMM with global_load_lds(16B) staging + XOR-swizzled LDS
// ---------------------------------------------------------------------------
enum { M_BIAS = 0, M_RES = 1, M_GELU = 2, M_DUAL = 3 };

template <int MODE>
__global__ void gemm_kernel(const bf16* __restrict__ A1, const bf16* __restrict__ Wt1,
                            const bf16* __restrict__ A2, const bf16* __restrict__ Wt2,
                            const float* __restrict__ bias1, const float* __restrict__ bias2,
                            const float* __restrict__ res,
                            float* __restrict__ outf, bf16* __restrict__ outb, int KTOT) {
    __shared__ __align__(16) bf16 As[128][64];
    __shared__ __align__(16) bf16 Bs[128][64];
    const int tid  = threadIdx.x;
    const int lane = tid & 63;
    const int wid  = tid >> 6;
    const int wm   = (wid >> 1) * 64;
    const int wn   = (wid & 1) * 64;
    const int m0   = blockIdx.y * 128;
    const int n0   = blockIdx.x * 128;

    floatx4 acc[4][4] = {};

    for (int k0 = 0; k0 < KTOT; k0 += 64) {
        const bf16* Ap;
        const bf16* Wp;
        int kk = k0;
        if (MODE == M_DUAL && k0 >= 512) { Ap = A2; Wp = Wt2; kk = k0 - 512; }
        else                             { Ap = A1; Wp = Wt1; }
#pragma unroll
        for (int i = 0; i < 4; i++) {
            const int s   = wid * 256 + i * 64 + lane;   // 16B slot index
            const int r   = s >> 3;
            const int cbg = (s & 7) ^ (r & 7);           // swizzled source col-block
            glds16(Ap + (size_t)(m0 + r) * 512 + kk + cbg * 8,
                   (char*)&As[0][0] + (size_t)(wid * 256 + i * 64) * 16);
            glds16(Wp + (size_t)(n0 + r) * 512 + kk + cbg * 8,
                   (char*)&Bs[0][0] + (size_t)(wid * 256 + i * 64) * 16);
        }
        __syncthreads();
#pragma unroll
        for (int ks = 0; ks < 64; ks += 32) {
            short8 af[4], bfr[4];
#pragma unroll
            for (int mt = 0; mt < 4; mt++) {
                const int row = wm + mt * 16 + (lane & 15);
                const int cph = ((ks >> 3) + (lane >> 4)) ^ (row & 7);
                af[mt] = *(const short8*)&As[row][cph * 8];
            }
#pragma unroll
            for (int nt = 0; nt < 4; nt++) {
                const int row = wn + nt * 16 + (lane & 15);
                const int cph = ((ks >> 3) + (lane >> 4)) ^ (row & 7);
                bfr[nt] = *(const short8*)&Bs[row][cph * 8];
            }
#pragma unroll
            for (int mt = 0; mt < 4; mt++)
#pragma unroll
                for (int nt = 0; nt < 4; nt++)
                    acc[mt][nt] = __builtin_amdgcn_mfma_f32_16x16x32_bf16(
                        af[mt], bfr[nt], acc[mt][nt], 0, 0, 0);
        }
        __syncthreads();
    }

#pragma unroll
    for (int mt = 0; mt < 4; mt++) {
        const int rbase = m0 + wm + mt * 16 + ((lane >> 4) << 2);
#pragma unroll
        for (int nt = 0; nt < 4; nt++) {
            const int col = n0 + wn + nt * 16 + (lane & 15);
            float bsum = bias1[col];
            if constexpr (MODE == M_DUAL) bsum += bias2[col];
#pragma unroll
            for (int r = 0; r < 4; r++) {
                const int row = rbase + r;
                float v = acc[mt][nt][r] + bsum;
                if constexpr (MODE == M_RES) v += res[(size_t)row * H + col];
                if constexpr (MODE == M_GELU) v = gelu_f(v);
                const size_t o = (size_t)row * H + col;
                if constexpr (MODE == M_RES || MODE == M_DUAL) outf[o] = v;
                if constexpr (MODE != M_DUAL) outb[o] = __float2bfloat16(v);
            }
        }
    }
}

// ---------------------------------------------------------------------------
extern "C" void kernel_launch(void* const* d_in, const int* in_sizes, int n_in,
                              void* d_out, int out_size, void* d_ws, size_t ws_size,
                              hipStream_t stream) {
    const float* x     = (const float*)d_in[0];
    const float* ln1w  = (const float*)d_in[1];
    const float* ln1b  = (const float*)d_in[2];
    const float* ln2w  = (const float*)d_in[3];
    const float* ln2b  = (const float*)d_in[4];
    const float* logdt = (const float*)d_in[5];
    const float* Are   = (const float*)d_in[6];
    const float* Aim   = (const float*)d_in[7];
    const float* Bre   = (const float*)d_in[8];
    const float* Bim   = (const float*)d_in[9];
    const float* Cre   = (const float*)d_in[10];
    const float* Cim   = (const float*)d_in[11];
    const float* Dvec  = (const float*)d_in[12];
    const float* Wk    = (const float*)d_in[13];
    const float* bk    = (const float*)d_in[14];
    const float* W1    = (const float*)d_in[15];
    const float* b1    = (const float*)d_in[16];
    const float* W2    = (const float*)d_in[17];
    const float* b2    = (const float*)d_in[18];
    const float* Wout  = (const float*)d_in[19];
    const float* bout  = (const float*)d_in[20];
    const float* Wproj = (const float*)d_in[21];
    const float* bproj = (const float*)d_in[22];
    float* outp = (float*)d_out;

    // Workspace packing (total ~230.5 MB, identical to round-1 proven footprint)
    char* p = (char*)d_ws;
    auto carve = [&](size_t bytes) -> char* {
        char* r = p;
        p += (bytes + 255) & ~(size_t)255;
        return r;
    };
    bf16*  zbA  = (bf16*)carve((size_t)MROWS * H * 2);
    bf16*  Ub   = (bf16*)carve((size_t)H * 512 * 64 * 2);
    float* Sloc = (float*)carve((size_t)H * 64 * 512 * 4);
    bf16*  S0b  = (bf16*)carve((size_t)H * 512 * 128 * 2);
    bf16*  M1b  = (bf16*)carve((size_t)LYR * H * 64 * 64 * 2);
    bf16*  TEb  = (bf16*)carve((size_t)LYR * H * 64 * 192 * 2);
    float* dAb  = (float*)carve((size_t)LYR * H * NH * 2 * 4);
    float* cfb  = (float*)carve((size_t)LYR * H * NH * 2 * 4);
    float* dAQb = (float*)carve((size_t)LYR * H * NH * 2 * 4);
    bf16* wts[5];
    for (int i = 0; i < 5; i++) wts[i] = (bf16*)carve((size_t)LYR * H * H * 2);

    bf16*  Yt   = zbA;                              // z dead after trans_in
    bf16*  bb1  = Ub;                               // Ub dead after conv_p3
    float* zbuf = Sloc;                             // Sloc dead after conv_scan2
    bf16*  bb0  = S0b;                              // S0b dead after conv_p3
    bf16*  bb2  = S0b + (size_t)MROWS * H;          // second half of S0b

    const float* wsrc[5] = {Wk, W1, W2, Wout, Wproj};
    {
        dim3 g(8, 8, LYR);
        for (int i = 0; i < 5; i++)
            cast_w_kernel<<<g, 256, 0, stream>>>(wsrc[i], wts[i]);
    }
    ssm_params_kernel<<<(LYR * H * NH) / 256, 256, 0, stream>>>(
        logdt, Are, Aim, Bre, Bim, Cre, Cim, dAb, cfb, dAQb);
    prep_mats<<<LYR * H, 64, 0, stream>>>(dAb, cfb, Dvec, M1b, TEb);

    const float* cur = x;
    for (int l = 0; l < LYR; l++) {
        ln_kernel<<<MROWS / 4, 256, 0, stream>>>(cur, ln1w + l * H, ln1b + l * H, zbA);
        trans_in_k<<<BATCH * NC * 8, 256, 0, stream>>>(zbA, Ub);
        conv_p1<<<H * 4, 256, 0, stream>>>(M1b + (size_t)l * H * 64 * 64, Ub, Sloc);
        conv_scan2<<<H * BATCH, 256, 0, stream>>>(Sloc, dAQb + (size_t)l * H * NH * 2, S0b);
        conv_p3<<<H * 4, 256, 0, stream>>>(TEb + (size_t)l * H * 64 * 192, Ub, S0b, Yt);
        trans_out_k<<<BATCH * NC * 8, 256, 0, stream>>>(Yt, bb0);

        dim3 gg(H / 128, MROWS / 128);
        gemm_kernel<M_BIAS><<<gg, 256, 0, stream>>>(
            bb0, wts[0] + (size_t)l * H * H, nullptr, nullptr,
            bk + l * H, nullptr, nullptr, nullptr, bb1, 512);
        gemm_kernel<M_RES><<<gg, 256, 0, stream>>>(
            bb1, wts[1] + (size_t)l * H * H, nullptr, nullptr,
            b1 + l * H, nullptr, cur, zbuf, bb0, 512);
        ln_kernel<<<MROWS / 4, 256, 0, stream>>>(zbuf, ln2w + l * H, ln2b + l * H, bb1);
        gemm_kernel<M_GELU><<<gg, 256, 0, stream>>>(
            bb1, wts[2] + (size_t)l * H * H, nullptr, nullptr,
            b2 + l * H, nullptr, nullptr, nullptr, bb2, 512);
        gemm_kernel<M_DUAL><<<gg, 256, 0, stream>>>(
            bb2, wts[3] + (size_t)l * H * H, bb0, wts[4] + (size_t)l * H * H,
            bout + l * H, bproj + l * H, nullptr, outp, nullptr, 1024);
        cur = outp;
    }
}

// Round 5
// 818.641 us; speedup vs baseline: 1.2776x; 1.1648x over previous
//
#include <hip/hip_runtime.h>
#include <hip/hip_bf16.h>
#include <math.h>

#define LYR   2
#define H     512
#define NH    32
#define BATCH 8
#define SEQL  4096
#define QC    64
#define NC    (SEQL / QC)
#define MROWS (BATCH * SEQL)

typedef __attribute__((ext_vector_type(8))) short short8;
typedef __attribute__((ext_vector_type(4))) float floatx4;
typedef __hip_bfloat16 bf16;

__device__ __forceinline__ float gelu_f(float x) {
    return 0.5f * x * (1.0f + erff(x * 0.70710678118654752440f));
}

__device__ __forceinline__ void glds16(const void* g, void* l) {
    __builtin_amdgcn_global_load_lds((const __attribute__((address_space(1))) void*)g,
                                     (__attribute__((address_space(3))) void*)l, 16, 0, 0);
}

// ---------------------------------------------------------------------------
// Weight cast + transpose: W[l][k][n] fp32 -> Wt[l][n][k] bf16
// ---------------------------------------------------------------------------
__global__ void cast_w_kernel(const float* __restrict__ W, bf16* __restrict__ Wt) {
    __shared__ __align__(16) float tile[64][65];
    const int l  = blockIdx.z;
    const int k0 = blockIdx.y * 64;
    const int n0 = blockIdx.x * 64;
    const float* src = W + (size_t)l * H * H;
    bf16* dst = Wt + (size_t)l * H * H;
#pragma unroll
    for (int i = 0; i < 16; i++) {
        int e = i * 256 + threadIdx.x;
        int r = e >> 6, c = e & 63;
        tile[r][c] = src[(size_t)(k0 + r) * H + n0 + c];
    }
    __syncthreads();
#pragma unroll
    for (int i = 0; i < 16; i++) {
        int e = i * 256 + threadIdx.x;
        int r = e >> 6, c = e & 63;
        dst[(size_t)(n0 + r) * H + k0 + c] = __float2bfloat16(tile[c][r]);
    }
}

// ---------------------------------------------------------------------------
// SSM discretization: dtA = dt*A, coef = C*B*(exp(dtA)-1)/A, dAQ = exp(dtA)^QC
// ---------------------------------------------------------------------------
__global__ void ssm_params_kernel(const float* __restrict__ log_dt,
                                  const float* __restrict__ A_re, const float* __restrict__ A_im,
                                  const float* __restrict__ B_re, const float* __restrict__ B_im,
                                  const float* __restrict__ C_re, const float* __restrict__ C_im,
                                  float* __restrict__ dtA, float* __restrict__ coef,
                                  float* __restrict__ dAQ) {
    const int idx = blockIdx.x * 256 + threadIdx.x;
    if (idx >= LYR * H * NH) return;
    const int lh = idx >> 5;
    const float dt  = expf(log_dt[lh]);
    const float are = A_re[idx], aim = A_im[idx];
    const float e   = expf(dt * are);
    const float dre = e * cosf(dt * aim);
    const float dim_ = e * sinf(dt * aim);
    const float den = are * are + aim * aim;
    const float nre = dre - 1.0f, nim = dim_;
    const float qre = (nre * are + nim * aim) / den;
    const float qim = (nim * are - nre * aim) / den;
    const float bre = B_re[idx], bim = B_im[idx];
    const float dbre = bre * qre - bim * qim;
    const float dbim = bre * qim + bim * qre;
    const float cre = C_re[idx], cim = C_im[idx];
    coef[2 * idx]     = cre * dbre - cim * dbim;
    coef[2 * idx + 1] = cre * dbim + cim * dbre;
    dtA[2 * idx]     = dt * are;
    dtA[2 * idx + 1] = dt * aim;
    const float eq = expf((float)QC * dt * are);
    const float ph = (float)QC * dt * aim;
    dAQ[2 * idx]     = eq * cosf(ph);
    dAQ[2 * idx + 1] = eq * sinf(ph);
}

// ---------------------------------------------------------------------------
// Build per-(l,h) conv matrices — closed-form powers, fully parallel.
//   M1b[lh][j][tau]  (64x64): j=2n -> Re(dA^{63-tau}), j=2n+1 -> Im
//   TEb[lh][t][192]: [0:64] T[t][tau]=K[t-tau] (t>=tau) + D_h diag
//                    [64:128] E (for S0 hi), [128:192] E (for S0 lo)
// 1024 blocks x 256 threads; thread = (t = tid>>2, 8 modes of ng = tid&3).
// dA^t = exp(t*dtA_re) * (cos(t*dtA_im), sin(t*dtA_im))  — no serial chain.
// ---------------------------------------------------------------------------
__global__ void prep_mats(const float* __restrict__ dtA, const float* __restrict__ coef,
                          const float* __restrict__ Dv,
                          bf16* __restrict__ M1b, bf16* __restrict__ TEb) {
    const int lh  = blockIdx.x;
    const int tid = threadIdx.x;
    const int t   = tid >> 2;
    const int ng  = tid & 3;
    __shared__ float Ksh[64];
    __shared__ __align__(16) bf16 TE[64][192];
    __shared__ __align__(16) bf16 M1s[64][64];

    const float ft = (float)t;
    float Kt = 0.f;
#pragma unroll
    for (int k = 0; k < 8; k++) {
        const int n = ng * 8 + k;
        const float dtr = dtA[((size_t)lh * NH + n) * 2];
        const float dti = dtA[((size_t)lh * NH + n) * 2 + 1];
        const float cre = coef[((size_t)lh * NH + n) * 2];
        const float cim = coef[((size_t)lh * NH + n) * 2 + 1];
        // dA
        const float er  = expf(dtr);
        const float dre = er * cosf(dti), dim_ = er * sinf(dti);
        // dA^t
        const float et = expf(ft * dtr);
        const float pr = et * cosf(ft * dti), pi = et * sinf(ft * dti);
        Kt = fmaf(2.f * cre, pr, fmaf(-2.f * cim, pi, Kt));
        // dA^{t+1}
        const float per = pr * dre - pi * dim_;
        const float pei = pr * dim_ + pi * dre;
        const float e0 = 2.f * (cre * per - cim * pei);
        const float e1 = -2.f * (cre * pei + cim * per);
        const bf16 b0 = __float2bfloat16(e0), b1 = __float2bfloat16(e1);
        TE[t][64 + 2 * n]  = b0;
        TE[t][65 + 2 * n]  = b1;
        TE[t][128 + 2 * n] = b0;
        TE[t][129 + 2 * n] = b1;
        // dA^{63-t}
        const float fq = (float)(63 - t);
        const float eq = expf(fq * dtr);
        const float qr = eq * cosf(fq * dti), qi = eq * sinf(fq * dti);
        M1s[2 * n][t]     = __float2bfloat16(qr);
        M1s[2 * n + 1][t] = __float2bfloat16(qi);
    }
    Kt += __shfl_xor(Kt, 1);
    Kt += __shfl_xor(Kt, 2);
    if (ng == 0) Ksh[t] = Kt;
    __syncthreads();
    const float Dh = Dv[lh];
#pragma unroll
    for (int i = 0; i < 16; i++) {
        const int tau = ng * 16 + i;
        float v = (tau > t) ? 0.f : Ksh[t - tau];
        if (tau == t) v += Dh;
        TE[t][tau] = __float2bfloat16(v);
    }
    __syncthreads();
    // coalesced write-out (16 B/lane)
    bf16* tep = TEb + (size_t)lh * 64 * 192;
    const bf16* tes = &TE[0][0];
#pragma unroll
    for (int i = 0; i < 6; i++) {
        const int idx = i * 256 + tid;
        *(floatx4*)(tep + (size_t)idx * 8) = *(const floatx4*)(tes + (size_t)idx * 8);
    }
    bf16* m1p = M1b + (size_t)lh * 64 * 64;
    const bf16* m1s = &M1s[0][0];
#pragma unroll
    for (int i = 0; i < 2; i++) {
        const int idx = i * 256 + tid;
        *(floatx4*)(m1p + (size_t)idx * 8) = *(const floatx4*)(m1s + (size_t)idx * 8);
    }
}

// ---------------------------------------------------------------------------
// LayerNorm over H=512, one wave per row, bf16 out
// ---------------------------------------------------------------------------
__global__ void ln_kernel(const float* __restrict__ src,
                          const float* __restrict__ gamma, const float* __restrict__ beta,
                          bf16* __restrict__ outb) {
    const int lane = threadIdx.x & 63;
    const int row  = blockIdx.x * 4 + (threadIdx.x >> 6);
    const float4* rp = (const float4*)(src + (size_t)row * H);
    float4 v0 = rp[lane];
    float4 v1 = rp[64 + lane];
    float s = v0.x + v0.y + v0.z + v0.w + v1.x + v1.y + v1.z + v1.w;
    float q = v0.x * v0.x + v0.y * v0.y + v0.z * v0.z + v0.w * v0.w +
              v1.x * v1.x + v1.y * v1.y + v1.z * v1.z + v1.w * v1.w;
#pragma unroll
    for (int off = 32; off > 0; off >>= 1) {
        s += __shfl_xor(s, off);
        q += __shfl_xor(q, off);
    }
    const float mean = s * (1.0f / H);
    const float var  = q * (1.0f / H) - mean * mean;
    const float rstd = rsqrtf(var + 1e-5f);
    const float4* gp = (const float4*)gamma;
    const float4* bp = (const float4*)beta;
    float4 g0 = gp[lane], g1 = gp[64 + lane];
    float4 b0 = bp[lane], b1 = bp[64 + lane];
    bf16 t0[4] = {__float2bfloat16((v0.x - mean) * rstd * g0.x + b0.x),
                  __float2bfloat16((v0.y - mean) * rstd * g0.y + b0.y),
                  __float2bfloat16((v0.z - mean) * rstd * g0.z + b0.z),
                  __float2bfloat16((v0.w - mean) * rstd * g0.w + b0.w)};
    bf16 t1[4] = {__float2bfloat16((v1.x - mean) * rstd * g1.x + b1.x),
                  __float2bfloat16((v1.y - mean) * rstd * g1.y + b1.y),
                  __float2bfloat16((v1.z - mean) * rstd * g1.z + b1.z),
                  __float2bfloat16((v1.w - mean) * rstd * g1.w + b1.w)};
    *(uint2*)(outb + (size_t)row * H + lane * 4)       = *(uint2*)t0;
    *(uint2*)(outb + (size_t)row * H + 256 + lane * 4) = *(uint2*)t1;
}

// ---------------------------------------------------------------------------
// Transpose z[b,t,h] bf16 -> Ub[h][bc][tau] bf16   (bc = b*64+c, t = c*64+tau)
// ---------------------------------------------------------------------------
__global__ void trans_in_k(const bf16* __restrict__ z, bf16* __restrict__ Ub) {
    const int hb = blockIdx.x & 7, bc = blockIdx.x >> 3;
    const int b = bc >> 6, c = bc & 63;
    const int h0 = hb * 64;
    __shared__ __align__(16) ushort Ti[64][68];
    const ushort* zp = (const ushort*)z + ((size_t)b * SEQL + c * QC) * H + h0;
#pragma unroll
    for (int i = 0; i < 4; i++) {
        int tau = i * 16 + (threadIdx.x >> 4), h4 = (threadIdx.x & 15) * 4;
        *(ushort4*)&Ti[tau][h4] = *(const ushort4*)(zp + (size_t)tau * H + h4);
    }
    __syncthreads();
    ushort* up = (ushort*)Ub + ((size_t)h0 * 512 + bc) * 64;
#pragma unroll
    for (int i = 0; i < 4; i++) {
        int hh = i * 16 + (threadIdx.x >> 4), t4 = (threadIdx.x & 15) * 4;
        ushort4 v;
        v.x = Ti[t4][hh]; v.y = Ti[t4 + 1][hh]; v.z = Ti[t4 + 2][hh]; v.w = Ti[t4 + 3][hh];
        *(ushort4*)(up + (size_t)hh * 512 * 64 + t4) = v;
    }
}

// ---------------------------------------------------------------------------
// Conv phase 1: Sloc[h][j][bc] (fp32) = M1[h](64x64) @ U[h](64 x 512-block)
// ---------------------------------------------------------------------------
__global__ void conv_p1(const bf16* __restrict__ M1l, const bf16* __restrict__ Ub,
                        float* __restrict__ Sloc) {
    const int h = blockIdx.x >> 2;
    const int n0 = (blockIdx.x & 3) * 128;
    __shared__ __align__(16) bf16 As[64][72];
    __shared__ __align__(16) bf16 Bs[128][72];
    const int tid = threadIdx.x, lane = tid & 63, wid = tid >> 6;
    const int wm = (wid & 1) * 32, wn = (wid >> 1) * 64;
#pragma unroll
    for (int i = 0; i < 2; i++) {
        int idx = i * 256 + tid, r = idx >> 3, c8 = (idx & 7) * 8;
        *(floatx4*)&As[r][c8] = *(const floatx4*)(M1l + ((size_t)h * 64 + r) * 64 + c8);
    }
#pragma unroll
    for (int i = 0; i < 4; i++) {
        int idx = i * 256 + tid, r = idx >> 3, c8 = (idx & 7) * 8;
        *(floatx4*)&Bs[r][c8] = *(const floatx4*)(Ub + ((size_t)h * 512 + n0 + r) * 64 + c8);
    }
    __syncthreads();
    floatx4 acc[2][4] = {};
#pragma unroll
    for (int ks = 0; ks < 64; ks += 32) {
        short8 af[2], bfr[4];
#pragma unroll
        for (int mt = 0; mt < 2; mt++)
            af[mt] = *(const short8*)&As[wm + mt * 16 + (lane & 15)][ks + (lane >> 4) * 8];
#pragma unroll
        for (int nt = 0; nt < 4; nt++)
            bfr[nt] = *(const short8*)&Bs[wn + nt * 16 + (lane & 15)][ks + (lane >> 4) * 8];
#pragma unroll
        for (int mt = 0; mt < 2; mt++)
#pragma unroll
            for (int nt = 0; nt < 4; nt++)
                acc[mt][nt] = __builtin_amdgcn_mfma_f32_16x16x32_bf16(af[mt], bfr[nt], acc[mt][nt], 0, 0, 0);
    }
#pragma unroll
    for (int mt = 0; mt < 2; mt++)
#pragma unroll
        for (int nt = 0; nt < 4; nt++) {
            const int bc = n0 + wn + nt * 16 + (lane & 15);
#pragma unroll
            for (int r = 0; r < 4; r++) {
                const int j = wm + mt * 16 + ((lane >> 4) << 2) + r;
                Sloc[((size_t)h * 64 + j) * 512 + bc] = acc[mt][nt][r];
            }
        }
}

// ---------------------------------------------------------------------------
// Chunk scan: local end-states -> incoming states, hi/lo bf16 split
// ---------------------------------------------------------------------------
__global__ void conv_scan2(const float* __restrict__ Sloc, const float* __restrict__ dAQl,
                           bf16* __restrict__ S0b) {
    const int h = blockIdx.x >> 3, b = blockIdx.x & 7;
    const int tid = threadIdx.x;
    __shared__ __align__(16) float Sl[64][65];
    __shared__ __align__(16) bf16 Ob[64][128];
#pragma unroll
    for (int i = 0; i < 16; i++) {
        int j = i * 4 + (tid >> 6), c = tid & 63;
        Sl[j][c] = Sloc[((size_t)h * 64 + j) * 512 + b * 64 + c];
    }
    __syncthreads();
    if (tid < 32) {
        const int n = tid;
        const float qr = dAQl[(h * NH + n) * 2], qi = dAQl[(h * NH + n) * 2 + 1];
        float rr = 0.f, ri = 0.f;
        for (int c = 0; c < 64; c++) {
            bf16 hr = __float2bfloat16(rr);
            bf16 hi = __float2bfloat16(ri);
            Ob[c][2 * n]          = hr;
            Ob[c][2 * n + 1]      = hi;
            Ob[c][64 + 2 * n]     = __float2bfloat16(rr - __bfloat162float(hr));
            Ob[c][64 + 2 * n + 1] = __float2bfloat16(ri - __bfloat162float(hi));
            const float lr = Sl[2 * n][c], li = Sl[2 * n + 1][c];
            const float tr = qr * rr - qi * ri + lr;
            ri = qr * ri + qi * rr + li;
            rr = tr;
        }
    }
    __syncthreads();
    bf16* op = S0b + ((size_t)h * 512 + b * 64) * 128;
#pragma unroll
    for (int i = 0; i < 4; i++) {
        int idx = i * 256 + tid, c = idx >> 4, c8 = (idx & 15) * 8;
        *(floatx4*)(op + (size_t)c * 128 + c8) = *(const floatx4*)&Ob[c][c8];
    }
}

// ---------------------------------------------------------------------------
// Conv phase 3: Y[h] = [T|E|E](64x192) @ [U; S0hi; S0lo], gelu, -> Yt[h][bc][t]
// ---------------------------------------------------------------------------
__global__ void conv_p3(const bf16* __restrict__ TEl, const bf16* __restrict__ Ub,
                        const bf16* __restrict__ S0b, bf16* __restrict__ Yt) {
    const int h = blockIdx.x >> 2;
    const int n0 = (blockIdx.x & 3) * 128;
    __shared__ __align__(16) char sm3[(64 + 128) * 200 * 2];
    bf16(*As)[200] = (bf16(*)[200])sm3;
    bf16(*Bs)[200] = (bf16(*)[200])(sm3 + 64 * 200 * 2);
    const int tid = threadIdx.x, lane = tid & 63, wid = tid >> 6;
    const int wm = (wid & 1) * 32, wn = (wid >> 1) * 64;
#pragma unroll
    for (int i = 0; i < 6; i++) {
        int idx = i * 256 + tid, r = idx / 24, c = (idx - r * 24) * 8;
        *(floatx4*)&As[r][c] = *(const floatx4*)(TEl + ((size_t)h * 64 + r) * 192 + c);
    }
#pragma unroll
    for (int i = 0; i < 4; i++) {
        int idx = i * 256 + tid, r = idx >> 3, c8 = (idx & 7) * 8;
        *(floatx4*)&Bs[r][c8] = *(const floatx4*)(Ub + ((size_t)h * 512 + n0 + r) * 64 + c8);
    }
#pragma unroll
    for (int i = 0; i < 8; i++) {
        int idx = i * 256 + tid, r = idx >> 4, c8 = (idx & 15) * 8;
        *(floatx4*)&Bs[r][64 + c8] = *(const floatx4*)(S0b + ((size_t)h * 512 + n0 + r) * 128 + c8);
    }
    __syncthreads();
    floatx4 acc[2][4] = {};
#pragma unroll
    for (int ks = 0; ks < 192; ks += 32) {
        short8 af[2], bfr[4];
#pragma unroll
        for (int mt = 0; mt < 2; mt++)
            af[mt] = *(const short8*)&As[wm + mt * 16 + (lane & 15)][ks + (lane >> 4) * 8];
#pragma unroll
        for (int nt = 0; nt < 4; nt++)
            bfr[nt] = *(const short8*)&Bs[wn + nt * 16 + (lane & 15)][ks + (lane >> 4) * 8];
#pragma unroll
        for (int mt = 0; mt < 2; mt++)
#pragma unroll
            for (int nt = 0; nt < 4; nt++)
                acc[mt][nt] = __builtin_amdgcn_mfma_f32_16x16x32_bf16(af[mt], bfr[nt], acc[mt][nt], 0, 0, 0);
    }
    __syncthreads();
    bf16(*Tt)[72] = (bf16(*)[72])sm3;
#pragma unroll
    for (int mt = 0; mt < 2; mt++)
#pragma unroll
        for (int nt = 0; nt < 4; nt++) {
            const int n = wn + nt * 16 + (lane & 15);
#pragma unroll
            for (int r = 0; r < 4; r++) {
                const int t = wm + mt * 16 + ((lane >> 4) << 2) + r;
                Tt[n][t] = __float2bfloat16(gelu_f(acc[mt][nt][r]));
            }
        }
    __syncthreads();
#pragma unroll
    for (int i = 0; i < 4; i++) {
        int idx = i * 256 + tid, r = idx >> 3, c8 = (idx & 7) * 8;
        *(floatx4*)(Yt + ((size_t)h * 512 + n0 + r) * 64 + c8) = *(const floatx4*)&Tt[r][c8];
    }
}

// ---------------------------------------------------------------------------
// Transpose Yt[h][bc][t] -> y[b, c*64+t, h] bf16
// ---------------------------------------------------------------------------
__global__ void trans_out_k(const bf16* __restrict__ Yt, bf16* __restrict__ y) {
    const int hb = blockIdx.x & 7, bc = blockIdx.x >> 3;
    const int b = bc >> 6, c = bc & 63;
    const int h0 = hb * 64;
    __shared__ __align__(16) ushort Ti[64][68];
    const ushort* yp = (const ushort*)Yt + ((size_t)h0 * 512 + bc) * 64;
#pragma unroll
    for (int i = 0; i < 4; i++) {
        int hh = i * 16 + (threadIdx.x >> 4), t4 = (threadIdx.x & 15) * 4;
        *(ushort4*)&Ti[hh][t4] = *(const ushort4*)(yp + (size_t)hh * 512 * 64 + t4);
    }
    __syncthreads();
    ushort* op = (ushort*)y + ((size_t)b * SEQL + c * QC) * H + h0;
#pragma unroll
    for (int i = 0; i < 4; i++) {
        int tau = i * 16 + (threadIdx.x >> 4), h4 = (threadIdx.x & 15) * 4;
        ushort4 v;
        v.x = Ti[h4][tau]; v.y = Ti[h4 + 1][tau]; v.z = Ti[h4 + 2][tau]; v.w = Ti[h4 + 3][tau];
        *(ushort4*)(op + (size_t)tau * H + h4) = v;
    }
}

// ---------------------------------------------------------------------------
// bf16 MFMA GEMM with global_load_lds(16B) staging + XOR-swizzled LDS
// ---------------------------------------------------------------------------
enum { M_BIAS = 0, M_RES = 1, M_GELU = 2, M_DUAL = 3 };

template <int MODE>
__global__ void gemm_kernel(const bf16* __restrict__ A1, const bf16* __restrict__ Wt1,
                            const bf16* __restrict__ A2, const bf16* __restrict__ Wt2,
                            const float* __restrict__ bias1, const float* __restrict__ bias2,
                            const float* __restrict__ res,
                            float* __restrict__ outf, bf16* __restrict__ outb, int KTOT) {
    __shared__ __align__(16) bf16 As[128][64];
    __shared__ __align__(16) bf16 Bs[128][64];
    const int tid  = threadIdx.x;
    const int lane = tid & 63;
    const int wid  = tid >> 6;
    const int wm   = (wid >> 1) * 64;
    const int wn   = (wid & 1) * 64;
    const int m0   = blockIdx.y * 128;
    const int n0   = blockIdx.x * 128;

    floatx4 acc[4][4] = {};

    for (int k0 = 0; k0 < KTOT; k0 += 64) {
        const bf16* Ap;
        const bf16* Wp;
        int kk = k0;
        if (MODE == M_DUAL && k0 >= 512) { Ap = A2; Wp = Wt2; kk = k0 - 512; }
        else                             { Ap = A1; Wp = Wt1; }
#pragma unroll
        for (int i = 0; i < 4; i++) {
            const int s   = wid * 256 + i * 64 + lane;   // 16B slot index
            const int r   = s >> 3;
            const int cbg = (s & 7) ^ (r & 7);           // swizzled source col-block
            glds16(Ap + (size_t)(m0 + r) * 512 + kk + cbg * 8,
                   (char*)&As[0][0] + (size_t)(wid * 256 + i * 64) * 16);
            glds16(Wp + (size_t)(n0 + r) * 512 + kk + cbg * 8,
                   (char*)&Bs[0][0] + (size_t)(wid * 256 + i * 64) * 16);
        }
        __syncthreads();
#pragma unroll
        for (int ks = 0; ks < 64; ks += 32) {
            short8 af[4], bfr[4];
#pragma unroll
            for (int mt = 0; mt < 4; mt++) {
                const int row = wm + mt * 16 + (lane & 15);
                const int cph = ((ks >> 3) + (lane >> 4)) ^ (row & 7);
                af[mt] = *(const short8*)&As[row][cph * 8];
            }
#pragma unroll
            for (int nt = 0; nt < 4; nt++) {
                const int row = wn + nt * 16 + (lane & 15);
                const int cph = ((ks >> 3) + (lane >> 4)) ^ (row & 7);
                bfr[nt] = *(const short8*)&Bs[row][cph * 8];
            }
#pragma unroll
            for (int mt = 0; mt < 4; mt++)
#pragma unroll
                for (int nt = 0; nt < 4; nt++)
                    acc[mt][nt] = __builtin_amdgcn_mfma_f32_16x16x32_bf16(
                        af[mt], bfr[nt], acc[mt][nt], 0, 0, 0);
        }
        __syncthreads();
    }

#pragma unroll
    for (int mt = 0; mt < 4; mt++) {
        const int rbase = m0 + wm + mt * 16 + ((lane >> 4) << 2);
#pragma unroll
        for (int nt = 0; nt < 4; nt++) {
            const int col = n0 + wn + nt * 16 + (lane & 15);
            float bsum = bias1[col];
            if constexpr (MODE == M_DUAL) bsum += bias2[col];
#pragma unroll
            for (int r = 0; r < 4; r++) {
                const int row = rbase + r;
                float v = acc[mt][nt][r] + bsum;
                if constexpr (MODE == M_RES) v += res[(size_t)row * H + col];
                if constexpr (MODE == M_GELU) v = gelu_f(v);
                const size_t o = (size_t)row * H + col;
                if constexpr (MODE == M_RES || MODE == M_DUAL) outf[o] = v;
                if constexpr (MODE != M_DUAL) outb[o] = __float2bfloat16(v);
            }
        }
    }
}

// ---------------------------------------------------------------------------
extern "C" void kernel_launch(void* const* d_in, const int* in_sizes, int n_in,
                              void* d_out, int out_size, void* d_ws, size_t ws_size,
                              hipStream_t stream) {
    const float* x     = (const float*)d_in[0];
    const float* ln1w  = (const float*)d_in[1];
    const float* ln1b  = (const float*)d_in[2];
    const float* ln2w  = (const float*)d_in[3];
    const float* ln2b  = (const float*)d_in[4];
    const float* logdt = (const float*)d_in[5];
    const float* Are   = (const float*)d_in[6];
    const float* Aim   = (const float*)d_in[7];
    const float* Bre   = (const float*)d_in[8];
    const float* Bim   = (const float*)d_in[9];
    const float* Cre   = (const float*)d_in[10];
    const float* Cim   = (const float*)d_in[11];
    const float* Dvec  = (const float*)d_in[12];
    const float* Wk    = (const float*)d_in[13];
    const float* bk    = (const float*)d_in[14];
    const float* W1    = (const float*)d_in[15];
    const float* b1    = (const float*)d_in[16];
    const float* W2    = (const float*)d_in[17];
    const float* b2    = (const float*)d_in[18];
    const float* Wout  = (const float*)d_in[19];
    const float* bout  = (const float*)d_in[20];
    const float* Wproj = (const float*)d_in[21];
    const float* bproj = (const float*)d_in[22];
    float* outp = (float*)d_out;

    // Workspace packing (total ~230.5 MB, identical to round-1 proven footprint)
    char* p = (char*)d_ws;
    auto carve = [&](size_t bytes) -> char* {
        char* r = p;
        p += (bytes + 255) & ~(size_t)255;
        return r;
    };
    bf16*  zbA  = (bf16*)carve((size_t)MROWS * H * 2);
    bf16*  Ub   = (bf16*)carve((size_t)H * 512 * 64 * 2);
    float* Sloc = (float*)carve((size_t)H * 64 * 512 * 4);
    bf16*  S0b  = (bf16*)carve((size_t)H * 512 * 128 * 2);
    bf16*  M1b  = (bf16*)carve((size_t)LYR * H * 64 * 64 * 2);
    bf16*  TEb  = (bf16*)carve((size_t)LYR * H * 64 * 192 * 2);
    float* dtAb = (float*)carve((size_t)LYR * H * NH * 2 * 4);
    float* cfb  = (float*)carve((size_t)LYR * H * NH * 2 * 4);
    float* dAQb = (float*)carve((size_t)LYR * H * NH * 2 * 4);
    bf16* wts[5];
    for (int i = 0; i < 5; i++) wts[i] = (bf16*)carve((size_t)LYR * H * H * 2);

    bf16*  Yt   = zbA;                              // z dead after trans_in
    bf16*  bb1  = Ub;                               // Ub dead after conv_p3
    float* zbuf = Sloc;                             // Sloc dead after conv_scan2
    bf16*  bb0  = S0b;                              // S0b dead after conv_p3
    bf16*  bb2  = S0b + (size_t)MROWS * H;          // second half of S0b

    const float* wsrc[5] = {Wk, W1, W2, Wout, Wproj};
    {
        dim3 g(8, 8, LYR);
        for (int i = 0; i < 5; i++)
            cast_w_kernel<<<g, 256, 0, stream>>>(wsrc[i], wts[i]);
    }
    ssm_params_kernel<<<(LYR * H * NH) / 256, 256, 0, stream>>>(
        logdt, Are, Aim, Bre, Bim, Cre, Cim, dtAb, cfb, dAQb);
    prep_mats<<<LYR * H, 256, 0, stream>>>(dtAb, cfb, Dvec, M1b, TEb);

    const float* cur = x;
    for (int l = 0; l < LYR; l++) {
        ln_kernel<<<MROWS / 4, 256, 0, stream>>>(cur, ln1w + l * H, ln1b + l * H, zbA);
        trans_in_k<<<BATCH * NC * 8, 256, 0, stream>>>(zbA, Ub);
        conv_p1<<<H * 4, 256, 0, stream>>>(M1b + (size_t)l * H * 64 * 64, Ub, Sloc);
        conv_scan2<<<H * BATCH, 256, 0, stream>>>(Sloc, dAQb + (size_t)l * H * NH * 2, S0b);
        conv_p3<<<H * 4, 256, 0, stream>>>(TEb + (size_t)l * H * 64 * 192, Ub, S0b, Yt);
        trans_out_k<<<BATCH * NC * 8, 256, 0, stream>>>(Yt, bb0);

        dim3 gg(H / 128, MROWS / 128);
        gemm_kernel<M_BIAS><<<gg, 256, 0, stream>>>(
            bb0, wts[0] + (size_t)l * H * H, nullptr, nullptr,
            bk + l * H, nullptr, nullptr, nullptr, bb1, 512);
        gemm_kernel<M_RES><<<gg, 256, 0, stream>>>(
            bb1, wts[1] + (size_t)l * H * H, nullptr, nullptr,
            b1 + l * H, nullptr, cur, zbuf, bb0, 512);
        ln_kernel<<<MROWS / 4, 256, 0, stream>>>(zbuf, ln2w + l * H, ln2b + l * H, bb1);
        gemm_kernel<M_GELU><<<gg, 256, 0, stream>>>(
            bb1, wts[2] + (size_t)l * H * H, nullptr, nullptr,
            b2 + l * H, nullptr, nullptr, nullptr, bb2, 512);
        gemm_kernel<M_DUAL><<<gg, 256, 0, stream>>>(
            bb2, wts[3] + (size_t)l * H * H, bb0, wts[4] + (size_t)l * H * H,
            bout + l * H, bproj + l * H, nullptr, outp, nullptr, 1024);
        cur = outp;
    }
}